// Round 3
// baseline (385.895 us; speedup 1.0000x reference)
//
#include <hip/hip_runtime.h>

// B=4, C=256, N=4096 attention modulation.
// out[b,c,i] = newL[b,i]*src[b,c,i] + newB[b,i],
// newL[b,i] = sum_j softmax_j(E)*oldL[j], E = src_i . ref_j over C.
//
// R15 == R14 resubmitted (R14 bench died on container acquisition, no
// counters). Design rationale:
//  (a) flash: 2-tile phases in a 2x32KB double buffer (64KB/block) ->
//      barrier count halves (16->8) vs R12 while 2 blocks/CU co-residency
//      is preserved (64KB*2 <= 160KB, VGPR capped at 128 via
//      __launch_bounds__(512,4)). A-fragments from prep-built s16
//      (16 coalesced 1KB loads; R13's per-jslice fp32 rebuild cost +8MB
//      fetch and a strided prologue).
//  (b) prep: src+ref transposes (8 z-slices); 1x1 conv fused into the ref
//      slices as NON-atomic per-channel-group partials oldLp[4][B][N]
//      (flash sums 4 partials + bias) -> no ordering hazard, so prep's
//      z==0 slice can zero the sum accumulators and the hipMemsetAsync
//      dispatch dies.
//  (c) flash accumulates sumP/sumL/sumB via atomicAdd.
//  (d) post: grid z = C/4 -> 1024 blocks (256 was 1 wave/SIMD,
//      latency-bound on a 32MB stream).

#define B_ 4
#define C_ 256
#define N_ 4096
#define LOG2E 1.44269504f
#define SHIFT2 86.5617f      // 60 * log2(e)
#define JSLICE 8
#define BN_ (B_ * N_)
#define NT_ 16               // j-tiles per block (512 j)
#define PH_ 8                // phases of 2 tiles

typedef _Float16 half_t;
typedef _Float16 v8h  __attribute__((ext_vector_type(8)));
typedef float    v16f __attribute__((ext_vector_type(16)));

#define GLDS16(g, l) __builtin_amdgcn_global_load_lds(                         \
    (const __attribute__((address_space(1))) void*)(g),                        \
    (__attribute__((address_space(3))) void*)(l), 16, 0, 0)

// --------------------- prep: transpose to fp16 fragments (+ fused conv)
// grid (N/64, C/64, 8), block 256.  z<4: src (scaled by log2e) -> s16.
// z>=4: ref -> r16, plus 1x1-conv partial over this block's 64 channels
// written non-atomically to oldLp/oldBp[cgroup=blockIdx.y][b][n].
// z==0 blocks additionally zero the 3*BN sum accumulators.
// fragment layout t16[b][tile=n/32][kb=c/16][lane][e],
//   lane=((c>>3)&1)*32+(n&31), e=c&7.
__global__ void k_prep(const float* __restrict__ src,
                       const float* __restrict__ ref,
                       const float* __restrict__ wl,
                       const float* __restrict__ wb,
                       half_t* __restrict__ s16, half_t* __restrict__ r16,
                       float* __restrict__ oldLp, float* __restrict__ oldBp,
                       float* __restrict__ sums /* 3*BN, zeroed here */) {
    __shared__ float tile[64][65];
    __shared__ float red[8][64];
    int z  = blockIdx.z;
    int isRef = z >> 2;
    int b  = z & 3;
    const float* in  = isRef ? ref : src;
    half_t*      out = isRef ? r16 : s16;
    float scale      = isRef ? 1.0f : LOG2E;
    int c0 = blockIdx.y * 64;
    int n0 = blockIdx.x * 64;
    int tid = threadIdx.x;
    if (z == 0) {                        // zero sum accumulators (race-free:
        int gid = (blockIdx.y * 64 + blockIdx.x) * 256 + tid;  // flash runs later)
        if (gid < 3 * BN_) sums[gid] = 0.f;
    }
    int tx = tid & 15, ty = tid >> 4;
#pragma unroll
    for (int q = 0; q < 4; q++) {
        int c = ty + q * 16;
        float4 v = *(const float4*)(in + ((size_t)b * C_ + c0 + c) * N_ + n0 + tx * 4);
        tile[c][tx * 4 + 0] = v.x;
        tile[c][tx * 4 + 1] = v.y;
        tile[c][tx * 4 + 2] = v.z;
        tile[c][tx * 4 + 3] = v.w;
    }
    __syncthreads();
    // fragment write
    int r   = tid & 31;
    int lhi = (tid >> 5) & 1;
    int wv  = tid >> 6;                  // kb_local 0..3
#pragma unroll
    for (int nt = 0; nt < 2; nt++) {
        int nl = nt * 32 + r;
        v8h o;
#pragma unroll
        for (int e = 0; e < 8; e++)
            o[e] = (half_t)(tile[wv * 16 + lhi * 8 + e][nl] * scale);
        size_t tj = (size_t)(n0 >> 5) + nt;
        size_t kb = (size_t)(c0 >> 4) + wv;
        *(v8h*)(out + ((((size_t)b * 128 + tj) * 16 + kb) * 64 + (tid & 63)) * 8) = o;
    }
    if (!isRef) return;
    // fused 1x1-conv partial over this block's 64 channels (non-atomic)
    int n  = tid & 63;
    int cq = tid >> 6;                   // 0..3
    float aL = 0.f, aB = 0.f;
#pragma unroll
    for (int c = 0; c < 16; c++) {
        float v = tile[cq * 16 + c][n];
        aL += v * wl[c0 + cq * 16 + c];
        aB += v * wb[c0 + cq * 16 + c];
    }
    red[cq][n]     = aL;
    red[4 + cq][n] = aB;
    __syncthreads();
    size_t slot = ((size_t)blockIdx.y * B_ + b) * N_ + n0;
    if (tid < 64) {
        oldLp[slot + tid] = red[0][tid] + red[1][tid] + red[2][tid] + red[3][tid];
    } else if (tid < 128) {
        int u = tid - 64;
        oldBp[slot + u] = red[4][u] + red[5][u] + red[6][u] + red[7][u];
    }
}

// ------------------------------------------------------------------ flash
// grid 512 = B(4) x jslice(8) x iblock(16), block 512 = 8 waves.
// Wave owns 32 i-rows; A-fragments from s16 (16 coalesced 1KB loads).
// 2 j-tiles per phase staged by global_load_lds into a 2x32KB double
// buffer (64KB -> still 2 blocks/CU); 8 barriers instead of 16.
__global__ __launch_bounds__(512, 4) void k_flash(
        const half_t* __restrict__ sT, const half_t* __restrict__ rT,
        const float* __restrict__ oldLp, const float* __restrict__ oldBp,
        const float* __restrict__ bl, const float* __restrict__ bb,
        float* __restrict__ sumP, float* __restrict__ sumL,
        float* __restrict__ sumB) {
    __shared__ half_t lds[2][16384];     // 2 phases x (2 tiles x 8192)
    int bid    = blockIdx.x;
    int b      = bid & 3;                // XCD spread
    int jslice = (bid >> 2) & (JSLICE - 1);
    int iblock = bid >> 5;
    int tid    = threadIdx.x;
    int wv     = tid >> 6;               // 0..7
    int lane   = tid & 63;
    int l31    = lane & 31, lhi = lane >> 5;
    int ti     = iblock * 8 + wv;        // 32-row A tile index
    int i0     = ti * 32;
    int j0     = jslice * (N_ / JSLICE); // 512 j per block
    int tj0    = j0 >> 5;

    // A fragments: one coalesced 1KB load per kb, held in VGPRs all kernel.
    const half_t* aP = sT + (((size_t)b * 128 + ti) * 16) * 512 + (size_t)lane * 8;
    v8h a[16];
#pragma unroll
    for (int kb = 0; kb < 16; kb++) a[kb] = *(const v8h*)(aP + (size_t)kb * 512);

    const half_t* bBase = rT + (((size_t)b * 128 + tj0) * 16) * 512;  // block-uniform
    const float*  oLp = oldLp + (size_t)b * N_ + j0 + l31;
    const float*  oBp = oldBp + (size_t)b * N_ + j0 + l31;
    float bl0 = bl[0], bb0 = bb[0];

    float sp[16], sl[16], sb[16];
#pragma unroll
    for (int r = 0; r < 16; r++) { sp[r] = 0.f; sl[r] = 0.f; sb[r] = 0.f; }

    // Prologue: DMA phase 0 (2 tiles = 32 chunks of 1KB) into buffer 0.
#pragma unroll
    for (int q = 0; q < 4; q++) {
        int chunk = q * 8 + wv;
        GLDS16(bBase + (size_t)chunk * 512 + (size_t)lane * 8,
               &lds[0][(size_t)chunk * 512]);
    }

    for (int ph = 0; ph < PH_; ph++) {
        __syncthreads();                       // drains DMA -> buf[ph&1] ready
        if (ph + 1 < PH_) {                    // DMA next 2-tile phase
            const half_t* g = bBase + (size_t)(ph + 1) * 16384;
#pragma unroll
            for (int q = 0; q < 4; q++) {
                int chunk = q * 8 + wv;
                GLDS16(g + (size_t)chunk * 512 + (size_t)lane * 8,
                       &lds[(ph + 1) & 1][(size_t)chunk * 512]);
            }
        }
#pragma unroll
        for (int t = 0; t < 2; t++) {
            int jt = ph * 2 + t;
            const half_t* bt = lds[ph & 1] + (size_t)t * 8192 + (size_t)lane * 8;
            // oldL/oldB: sum of 4 channel-group partials + bias (L2-resident)
            float lam = oLp[jt * 32]           + oLp[BN_ + jt * 32]
                      + oLp[2 * BN_ + jt * 32] + oLp[3 * BN_ + jt * 32] + bl0;
            float bet = oBp[jt * 32]           + oBp[BN_ + jt * 32]
                      + oBp[2 * BN_ + jt * 32] + oBp[3 * BN_ + jt * 32] + bb0;
            // Two independent 8-deep MFMA chains (halve acc-dependency path).
            v16f acc0, acc1;
#pragma unroll
            for (int r = 0; r < 16; r++) { acc0[r] = -SHIFT2; acc1[r] = 0.f; }
#pragma unroll
            for (int kb = 0; kb < 8; kb++) {
                acc0 = __builtin_amdgcn_mfma_f32_32x32x16_f16(
                    a[kb],     *(const v8h*)(bt + (size_t)kb * 512),       acc0, 0, 0, 0);
                acc1 = __builtin_amdgcn_mfma_f32_32x32x16_f16(
                    a[kb + 8], *(const v8h*)(bt + (size_t)(kb + 8) * 512), acc1, 0, 0, 0);
            }
#pragma unroll
            for (int r = 0; r < 16; r++) {
                float p = __builtin_amdgcn_exp2f(acc0[r] + acc1[r]);
                sp[r] += p;
                sl[r] += p * lam;
                sb[r] += p * bet;
            }
        }
    }

#pragma unroll
    for (int r = 0; r < 16; r++) {
        float tp = sp[r], tl = sl[r], tb = sb[r];
#pragma unroll
        for (int m = 1; m <= 16; m <<= 1) {
            tp += __shfl_xor(tp, m, 64);
            tl += __shfl_xor(tl, m, 64);
            tb += __shfl_xor(tb, m, 64);
        }
        if (l31 == 0) {
            // C/D layout: row = (reg&3) + 8*(reg>>2) + 4*(lane>>5)
            int row = (r & 3) + 8 * (r >> 2) + 4 * lhi;
            size_t ig = (size_t)b * N_ + i0 + row;
            atomicAdd(&sumP[ig], tp);
            atomicAdd(&sumL[ig], tl);
            atomicAdd(&sumB[ig], tb);
        }
    }
}

// ------------------------- epilogue: normalize + modulate
// grid (B, N/1024, C/4) = 1024 blocks (4x the R12 grid -- it was 1
// wave/SIMD and latency-bound), block 256. Thread owns 4 consecutive
// pixels x 4 channels; newL/newB one float4 from each sum array.
__global__ void k_post(const float* __restrict__ src,
                       const float* __restrict__ sums,
                       float* __restrict__ out) {
    int b  = blockIdx.x;
    int n0 = blockIdx.y * 1024;
    int c0 = blockIdx.z * 4;
    int t  = threadIdx.x;
    size_t bn = (size_t)b * N_ + n0 + t * 4;
    float4 sp = *(const float4*)(sums + bn);
    float4 sl = *(const float4*)(sums + BN_ + bn);
    float4 sb = *(const float4*)(sums + 2 * BN_ + bn);
    float4 L, T;
    L.x = sl.x / sp.x; L.y = sl.y / sp.y; L.z = sl.z / sp.z; L.w = sl.w / sp.w;
    T.x = sb.x / sp.x; T.y = sb.y / sp.y; T.z = sb.z / sp.z; T.w = sb.w / sp.w;
    const float* sp0 = src + ((size_t)b * C_ + c0) * N_ + n0 + t * 4;
    float*       op0 = out + ((size_t)b * C_ + c0) * N_ + n0 + t * 4;
#pragma unroll
    for (int c = 0; c < 4; c++) {
        float4 v = *(const float4*)(sp0 + (size_t)c * N_);
        float4 o;
        o.x = L.x * v.x + T.x;
        o.y = L.y * v.y + T.y;
        o.z = L.z * v.z + T.z;
        o.w = L.w * v.w + T.w;
        *(float4*)(op0 + (size_t)c * N_) = o;
    }
}

extern "C" void kernel_launch(void* const* d_in, const int* in_sizes, int n_in,
                              void* d_out, int out_size, void* d_ws, size_t ws_size,
                              hipStream_t stream) {
    const float* src = (const float*)d_in[0];
    const float* ref = (const float*)d_in[1];
    const float* wl  = (const float*)d_in[2];
    const float* bl  = (const float*)d_in[3];
    const float* wb  = (const float*)d_in[4];
    const float* bb  = (const float*)d_in[5];
    float* out = (float*)d_out;

    float* oldLp = (float*)d_ws;            // [4][B][N] conv partials
    float* oldBp = oldLp + 4 * BN_;         // [4][B][N]
    float* sums  = oldBp + 4 * BN_;         // sumP|sumL|sumB, 3*BN
    float* sumP  = sums;
    float* sumL  = sums + BN_;
    float* sumB  = sums + 2 * BN_;
    size_t needF  = (size_t)11 * BN_ * sizeof(float);
    size_t need16 = (size_t)2 * B_ * N_ * C_ * sizeof(half_t);
    half_t* s16;
    if (ws_size >= needF + need16) s16 = (half_t*)((char*)d_ws + needF);
    else                           s16 = (half_t*)d_out;   // dead before k_post writes
    half_t* r16 = s16 + (size_t)B_ * N_ * C_;

    k_prep<<<dim3(N_ / 64, C_ / 64, 8), 256, 0, stream>>>(
        src, ref, wl, wb, s16, r16, oldLp, oldBp, sums);
    k_flash<<<B_ * JSLICE * 16, 512, 0, stream>>>(
        s16, r16, oldLp, oldBp, bl, bb, sumP, sumL, sumB);
    k_post<<<dim3(B_, N_ / 1024, C_ / 4), 256, 0, stream>>>(src, sums, out);
}

// Round 4
// 149.850 us; speedup vs baseline: 2.5752x; 2.5752x over previous
//
#include <hip/hip_runtime.h>

// B=4, C=256, N=4096 attention modulation.
// out[b,c,i] = newL[b,i]*src[b,c,i] + newB[b,i],
// newL[b,i] = sum_j softmax_j(E)*oldL[j], E = src_i . ref_j over C.
//
// R16 (post-mortem of R15: __launch_bounds__(512,4) capped the unified
// reg budget at 128/wave < the ~160 live set (a[16]=64 + acc=32 +
// sums=48 + addr) -> 560MB scratch spill, flash 302us. Single fix:
// launch bounds back to (512,2) = 256-reg budget, no spill. Occupancy is
// VGPR-bound (~12 waves/CU), NOT LDS-bound, so the 2x32KB double buffer
// does not cost co-residency vs R12's 2x16KB):
//  (a) flash: 2-tile phases in a 2x32KB double buffer (64KB/block) ->
//      barriers halve vs R12 (16->8) at unchanged occupancy.
//  (b) prep: src+ref transposes (8 z-slices); 1x1 conv fused into the ref
//      slices as NON-atomic per-channel-group partials oldLp[4][B][N]
//      (flash sums 4 partials + bias); z==0 slice zeroes the sum
//      accumulators -> no hipMemsetAsync dispatch.
//  (c) flash accumulates sumP/sumL/sumB via atomicAdd.
//  (d) post: grid z = C/4 -> 1024 blocks.

#define B_ 4
#define C_ 256
#define N_ 4096
#define LOG2E 1.44269504f
#define SHIFT2 86.5617f      // 60 * log2(e)
#define JSLICE 8
#define BN_ (B_ * N_)
#define NT_ 16               // j-tiles per block (512 j)
#define PH_ 8                // phases of 2 tiles

typedef _Float16 half_t;
typedef _Float16 v8h  __attribute__((ext_vector_type(8)));
typedef float    v16f __attribute__((ext_vector_type(16)));

#define GLDS16(g, l) __builtin_amdgcn_global_load_lds(                         \
    (const __attribute__((address_space(1))) void*)(g),                        \
    (__attribute__((address_space(3))) void*)(l), 16, 0, 0)

// --------------------- prep: transpose to fp16 fragments (+ fused conv)
// grid (N/64, C/64, 8), block 256.  z<4: src (scaled by log2e) -> s16.
// z>=4: ref -> r16, plus 1x1-conv partial over this block's 64 channels
// written non-atomically to oldLp/oldBp[cgroup=blockIdx.y][b][n].
// z==0 blocks additionally zero the 3*BN sum accumulators.
// fragment layout t16[b][tile=n/32][kb=c/16][lane][e],
//   lane=((c>>3)&1)*32+(n&31), e=c&7.
__global__ void k_prep(const float* __restrict__ src,
                       const float* __restrict__ ref,
                       const float* __restrict__ wl,
                       const float* __restrict__ wb,
                       half_t* __restrict__ s16, half_t* __restrict__ r16,
                       float* __restrict__ oldLp, float* __restrict__ oldBp,
                       float* __restrict__ sums /* 3*BN, zeroed here */) {
    __shared__ float tile[64][65];
    __shared__ float red[8][64];
    int z  = blockIdx.z;
    int isRef = z >> 2;
    int b  = z & 3;
    const float* in  = isRef ? ref : src;
    half_t*      out = isRef ? r16 : s16;
    float scale      = isRef ? 1.0f : LOG2E;
    int c0 = blockIdx.y * 64;
    int n0 = blockIdx.x * 64;
    int tid = threadIdx.x;
    if (z == 0) {                        // zero sum accumulators (race-free:
        int gid = (blockIdx.y * 64 + blockIdx.x) * 256 + tid;  // flash runs later)
        if (gid < 3 * BN_) sums[gid] = 0.f;
    }
    int tx = tid & 15, ty = tid >> 4;
#pragma unroll
    for (int q = 0; q < 4; q++) {
        int c = ty + q * 16;
        float4 v = *(const float4*)(in + ((size_t)b * C_ + c0 + c) * N_ + n0 + tx * 4);
        tile[c][tx * 4 + 0] = v.x;
        tile[c][tx * 4 + 1] = v.y;
        tile[c][tx * 4 + 2] = v.z;
        tile[c][tx * 4 + 3] = v.w;
    }
    __syncthreads();
    // fragment write
    int r   = tid & 31;
    int lhi = (tid >> 5) & 1;
    int wv  = tid >> 6;                  // kb_local 0..3
#pragma unroll
    for (int nt = 0; nt < 2; nt++) {
        int nl = nt * 32 + r;
        v8h o;
#pragma unroll
        for (int e = 0; e < 8; e++)
            o[e] = (half_t)(tile[wv * 16 + lhi * 8 + e][nl] * scale);
        size_t tj = (size_t)(n0 >> 5) + nt;
        size_t kb = (size_t)(c0 >> 4) + wv;
        *(v8h*)(out + ((((size_t)b * 128 + tj) * 16 + kb) * 64 + (tid & 63)) * 8) = o;
    }
    if (!isRef) return;
    // fused 1x1-conv partial over this block's 64 channels (non-atomic)
    int n  = tid & 63;
    int cq = tid >> 6;                   // 0..3
    float aL = 0.f, aB = 0.f;
#pragma unroll
    for (int c = 0; c < 16; c++) {
        float v = tile[cq * 16 + c][n];
        aL += v * wl[c0 + cq * 16 + c];
        aB += v * wb[c0 + cq * 16 + c];
    }
    red[cq][n]     = aL;
    red[4 + cq][n] = aB;
    __syncthreads();
    size_t slot = ((size_t)blockIdx.y * B_ + b) * N_ + n0;
    if (tid < 64) {
        oldLp[slot + tid] = red[0][tid] + red[1][tid] + red[2][tid] + red[3][tid];
    } else if (tid < 128) {
        int u = tid - 64;
        oldBp[slot + u] = red[4][u] + red[5][u] + red[6][u] + red[7][u];
    }
}

// ------------------------------------------------------------------ flash
// grid 512 = B(4) x jslice(8) x iblock(16), block 512 = 8 waves.
// Wave owns 32 i-rows; A-fragments from s16 (16 coalesced 1KB loads).
// 2 j-tiles per phase staged by global_load_lds into a 2x32KB double
// buffer; 8 barriers instead of 16. launch_bounds(512,2): 256-reg/wave
// budget -- the ~160-reg live set must NOT be squeezed (R15 spill).
__global__ __launch_bounds__(512, 2) void k_flash(
        const half_t* __restrict__ sT, const half_t* __restrict__ rT,
        const float* __restrict__ oldLp, const float* __restrict__ oldBp,
        const float* __restrict__ bl, const float* __restrict__ bb,
        float* __restrict__ sumP, float* __restrict__ sumL,
        float* __restrict__ sumB) {
    __shared__ half_t lds[2][16384];     // 2 phases x (2 tiles x 8192)
    int bid    = blockIdx.x;
    int b      = bid & 3;                // XCD spread
    int jslice = (bid >> 2) & (JSLICE - 1);
    int iblock = bid >> 5;
    int tid    = threadIdx.x;
    int wv     = tid >> 6;               // 0..7
    int lane   = tid & 63;
    int l31    = lane & 31, lhi = lane >> 5;
    int ti     = iblock * 8 + wv;        // 32-row A tile index
    int i0     = ti * 32;
    int j0     = jslice * (N_ / JSLICE); // 512 j per block
    int tj0    = j0 >> 5;

    // A fragments: one coalesced 1KB load per kb, held in VGPRs all kernel.
    const half_t* aP = sT + (((size_t)b * 128 + ti) * 16) * 512 + (size_t)lane * 8;
    v8h a[16];
#pragma unroll
    for (int kb = 0; kb < 16; kb++) a[kb] = *(const v8h*)(aP + (size_t)kb * 512);

    const half_t* bBase = rT + (((size_t)b * 128 + tj0) * 16) * 512;  // block-uniform
    const float*  oLp = oldLp + (size_t)b * N_ + j0 + l31;
    const float*  oBp = oldBp + (size_t)b * N_ + j0 + l31;
    float bl0 = bl[0], bb0 = bb[0];

    float sp[16], sl[16], sb[16];
#pragma unroll
    for (int r = 0; r < 16; r++) { sp[r] = 0.f; sl[r] = 0.f; sb[r] = 0.f; }

    // Prologue: DMA phase 0 (2 tiles = 32 chunks of 1KB) into buffer 0.
#pragma unroll
    for (int q = 0; q < 4; q++) {
        int chunk = q * 8 + wv;
        GLDS16(bBase + (size_t)chunk * 512 + (size_t)lane * 8,
               &lds[0][(size_t)chunk * 512]);
    }

    for (int ph = 0; ph < PH_; ph++) {
        __syncthreads();                       // drains DMA -> buf[ph&1] ready
        if (ph + 1 < PH_) {                    // DMA next 2-tile phase
            const half_t* g = bBase + (size_t)(ph + 1) * 16384;
#pragma unroll
            for (int q = 0; q < 4; q++) {
                int chunk = q * 8 + wv;
                GLDS16(g + (size_t)chunk * 512 + (size_t)lane * 8,
                       &lds[(ph + 1) & 1][(size_t)chunk * 512]);
            }
        }
#pragma unroll
        for (int t = 0; t < 2; t++) {
            int jt = ph * 2 + t;
            const half_t* bt = lds[ph & 1] + (size_t)t * 8192 + (size_t)lane * 8;
            // oldL/oldB: sum of 4 channel-group partials + bias (L2-resident)
            float lam = oLp[jt * 32]           + oLp[BN_ + jt * 32]
                      + oLp[2 * BN_ + jt * 32] + oLp[3 * BN_ + jt * 32] + bl0;
            float bet = oBp[jt * 32]           + oBp[BN_ + jt * 32]
                      + oBp[2 * BN_ + jt * 32] + oBp[3 * BN_ + jt * 32] + bb0;
            // Two independent 8-deep MFMA chains (halve acc-dependency path).
            v16f acc0, acc1;
#pragma unroll
            for (int r = 0; r < 16; r++) { acc0[r] = -SHIFT2; acc1[r] = 0.f; }
#pragma unroll
            for (int kb = 0; kb < 8; kb++) {
                acc0 = __builtin_amdgcn_mfma_f32_32x32x16_f16(
                    a[kb],     *(const v8h*)(bt + (size_t)kb * 512),       acc0, 0, 0, 0);
                acc1 = __builtin_amdgcn_mfma_f32_32x32x16_f16(
                    a[kb + 8], *(const v8h*)(bt + (size_t)(kb + 8) * 512), acc1, 0, 0, 0);
            }
#pragma unroll
            for (int r = 0; r < 16; r++) {
                float p = __builtin_amdgcn_exp2f(acc0[r] + acc1[r]);
                sp[r] += p;
                sl[r] += p * lam;
                sb[r] += p * bet;
            }
        }
    }

#pragma unroll
    for (int r = 0; r < 16; r++) {
        float tp = sp[r], tl = sl[r], tb = sb[r];
#pragma unroll
        for (int m = 1; m <= 16; m <<= 1) {
            tp += __shfl_xor(tp, m, 64);
            tl += __shfl_xor(tl, m, 64);
            tb += __shfl_xor(tb, m, 64);
        }
        if (l31 == 0) {
            // C/D layout: row = (reg&3) + 8*(reg>>2) + 4*(lane>>5)
            int row = (r & 3) + 8 * (r >> 2) + 4 * lhi;
            size_t ig = (size_t)b * N_ + i0 + row;
            atomicAdd(&sumP[ig], tp);
            atomicAdd(&sumL[ig], tl);
            atomicAdd(&sumB[ig], tb);
        }
    }
}

// ------------------------- epilogue: normalize + modulate
// grid (B, N/1024, C/4) = 1024 blocks, block 256. Thread owns 4
// consecutive pixels x 4 channels; newL/newB one float4 per sum array.
__global__ void k_post(const float* __restrict__ src,
                       const float* __restrict__ sums,
                       float* __restrict__ out) {
    int b  = blockIdx.x;
    int n0 = blockIdx.y * 1024;
    int c0 = blockIdx.z * 4;
    int t  = threadIdx.x;
    size_t bn = (size_t)b * N_ + n0 + t * 4;
    float4 sp = *(const float4*)(sums + bn);
    float4 sl = *(const float4*)(sums + BN_ + bn);
    float4 sb = *(const float4*)(sums + 2 * BN_ + bn);
    float4 L, T;
    L.x = sl.x / sp.x; L.y = sl.y / sp.y; L.z = sl.z / sp.z; L.w = sl.w / sp.w;
    T.x = sb.x / sp.x; T.y = sb.y / sp.y; T.z = sb.z / sp.z; T.w = sb.w / sp.w;
    const float* sp0 = src + ((size_t)b * C_ + c0) * N_ + n0 + t * 4;
    float*       op0 = out + ((size_t)b * C_ + c0) * N_ + n0 + t * 4;
#pragma unroll
    for (int c = 0; c < 4; c++) {
        float4 v = *(const float4*)(sp0 + (size_t)c * N_);
        float4 o;
        o.x = L.x * v.x + T.x;
        o.y = L.y * v.y + T.y;
        o.z = L.z * v.z + T.z;
        o.w = L.w * v.w + T.w;
        *(float4*)(op0 + (size_t)c * N_) = o;
    }
}

extern "C" void kernel_launch(void* const* d_in, const int* in_sizes, int n_in,
                              void* d_out, int out_size, void* d_ws, size_t ws_size,
                              hipStream_t stream) {
    const float* src = (const float*)d_in[0];
    const float* ref = (const float*)d_in[1];
    const float* wl  = (const float*)d_in[2];
    const float* bl  = (const float*)d_in[3];
    const float* wb  = (const float*)d_in[4];
    const float* bb  = (const float*)d_in[5];
    float* out = (float*)d_out;

    float* oldLp = (float*)d_ws;            // [4][B][N] conv partials
    float* oldBp = oldLp + 4 * BN_;         // [4][B][N]
    float* sums  = oldBp + 4 * BN_;         // sumP|sumL|sumB, 3*BN
    float* sumP  = sums;
    float* sumL  = sums + BN_;
    float* sumB  = sums + 2 * BN_;
    size_t needF  = (size_t)11 * BN_ * sizeof(float);
    size_t need16 = (size_t)2 * B_ * N_ * C_ * sizeof(half_t);
    half_t* s16;
    if (ws_size >= needF + need16) s16 = (half_t*)((char*)d_ws + needF);
    else                           s16 = (half_t*)d_out;   // dead before k_post writes
    half_t* r16 = s16 + (size_t)B_ * N_ * C_;

    k_prep<<<dim3(N_ / 64, C_ / 64, 8), 256, 0, stream>>>(
        src, ref, wl, wb, s16, r16, oldLp, oldBp, sums);
    k_flash<<<B_ * JSLICE * 16, 512, 0, stream>>>(
        s16, r16, oldLp, oldBp, bl, bb, sumP, sumL, sumB);
    k_post<<<dim3(B_, N_ / 1024, C_ / 4), 256, 0, stream>>>(src, sums, out);
}